// Round 9
// baseline (487.649 us; speedup 1.0000x reference)
//
#include <hip/hip_runtime.h>
#include <math.h>

#define NN 1024
#define DHH 32
#define DEE 16
#define TT 8
#define NOBS_ 64
#define ADIM_ 10
#define NSPLIT 4   // blocks per row in edge kernel; 4 tiles of 16 j per block

typedef _Float16 h4 __attribute__((ext_vector_type(4)));
typedef float f4 __attribute__((ext_vector_type(4)));

// 1-ulp hardware reciprocal: avoids the ~10-instr IEEE division expansion.
__device__ __forceinline__ float rcp_(float x) { return __builtin_amdgcn_rcpf(x); }
__device__ __forceinline__ float sig_(float x) { return rcp_(1.0f + __expf(-x)); }
__device__ __forceinline__ float tanh_(float x) { return 1.0f - 2.0f * rcp_(1.0f + __expf(2.0f * x)); }

// Fused prep: blocks 0..63  -> y (+f16 copy) + base for 16 nodes each; block 63 also argmax -> out[0]
//             blocks 64..111-> f16 weight tables (hh identity layout, ih de-strided)
//             blocks 112..115 -> zero per-row completion counters
__global__ __launch_bounds__(256) void prep2_kernel(
    const float* __restrict__ h, const float* __restrict__ W_out,
    const float* __restrict__ b_out, const int* __restrict__ types,
    const float* __restrict__ w_ih_e, const float* __restrict__ w_hh_e,
    const float* __restrict__ b_e, const float* __restrict__ rs,
    float* __restrict__ y, _Float16* __restrict__ y_h,
    float* __restrict__ base, _Float16* __restrict__ w16hh,
    _Float16* __restrict__ w16ih, int* __restrict__ cnt,
    float* __restrict__ out) {
  const int blk = blockIdx.x;
  const int tid = threadIdx.x;
  if (blk < 64) {
    __shared__ float ys[256];
    const int ni = tid >> 4, d = tid & 15;
    const int node = blk * 16 + ni;
    const float* hp = h + node * DHH;
    const float* wp = W_out + d * DHH;
    float s = b_out[d];
#pragma unroll
    for (int q = 0; q < DHH; ++q) s = fmaf(hp[q], wp[q], s);
    s = fmaxf(s, 0.0f);
    y[node * 16 + d] = s;
    y_h[node * 16 + d] = (_Float16)s;
    ys[tid] = s;
    __syncthreads();
#pragma unroll
    for (int v0 = 0; v0 < 3; ++v0) {
      const int v = v0 * 256 + tid;           // 768 (node,k) pairs per block
      const int ni2 = v / 48, k = v - ni2 * 48;
      const int node2 = blk * 16 + ni2;
      const int t = types[node2];
      const float* w = w_ih_e + (t * 48 + k) * 33;
      float s2 = b_e[t * 48 + k] + rs[0] * w[32];
#pragma unroll
      for (int q = 0; q < DEE; ++q) s2 = fmaf(w[q], ys[ni2 * 16 + q], s2);
      base[node2 * 48 + k] = s2;
    }
    if (blk == 63 && tid == 0) {   // nodes 1014..1023 are ni 6..15 here
      int bi = 0;
      float best = ys[6 * 16];
      for (int l = 1; l < ADIM_; ++l) {
        float v = ys[(6 + l) * 16];
        if (v > best) { best = v; bi = l; }
      }
      out[0] = (float)bi;
    }
  } else if (blk < 112) {
    const int u = (blk - 64) * 256 + tid;     // < 12288
    if (u < TT * 48 * 16) {
      w16hh[u] = (_Float16)w_hh_e[u];
    } else {
      const int v = u - TT * 48 * 16;
      const int row = v >> 4, k = v & 15;
      w16ih[v] = (_Float16)w_ih_e[row * 33 + 16 + k];
    }
  } else {
    cnt[(blk - 112) * 256 + tid] = 0;
  }
}

// MFMA edge GRU + fused node-GRU tail (last-block-done per row).
// Block b: row i = b>>2, quarter s = b&3; lane owns dims (lane>>4)*4.. of edge j.
__global__ __launch_bounds__(256, 4) void edge_kernel(
    const float* __restrict__ e, const int* __restrict__ A,
    const _Float16* __restrict__ w16hh, const _Float16* __restrict__ w16ih,
    const float* __restrict__ bn_e, const int* __restrict__ types,
    const float* __restrict__ base, const _Float16* __restrict__ yh,
    float* __restrict__ e_new, float* __restrict__ rowsum_part,
    int* __restrict__ cnt, const float* __restrict__ obs,
    const float* __restrict__ hsrc, const float* __restrict__ w_ih_n,
    const float* __restrict__ w_hh_n, const float* __restrict__ b_n,
    const float* __restrict__ bn_n, const float* __restrict__ y,
    float* __restrict__ out) {
  __shared__ float red[4][16];
  __shared__ int lastflag;
  const int b = blockIdx.x;
  const int i = b >> 2;
  const int s = b & 3;
  const int tid = threadIdx.x;
  const int lane = tid & 63, wid = tid >> 6;
  const int lj = lane & 15;
  const int kg = lane >> 4;
  const int jb = s * 256 + wid * 64 + lj;
  const int erow = i * NN;

  // ---- data loads first (blockIdx-only addresses) ----
  f4 evs[4]; h4 yvs[4]; float as[4];
#pragma unroll
  for (int tt = 0; tt < 4; ++tt) {
    const int j = jb + tt * 16;
    evs[tt] = *(const f4*)(e + (erow + j) * 16 + kg * 4);
    yvs[tt] = *(const h4*)(yh + j * 16 + kg * 4);
    as[tt] = (float)A[erow + j];
  }

  // ---- type-dependent preamble (resolves under the load shadow) ----
  const int t = types[i];
  const h4 ar = *(const h4*)(w16hh + (t * 48 + lj) * 16 + kg * 4);
  const h4 az = *(const h4*)(w16hh + (t * 48 + 16 + lj) * 16 + kg * 4);
  const h4 an = *(const h4*)(w16hh + (t * 48 + 32 + lj) * 16 + kg * 4);
  const h4 cr = *(const h4*)(w16ih + (t * 48 + lj) * 16 + kg * 4);
  const h4 cz = *(const h4*)(w16ih + (t * 48 + 16 + lj) * 16 + kg * 4);
  const h4 cn = *(const h4*)(w16ih + (t * 48 + 32 + lj) * 16 + kg * 4);
  const f4 bsr = *(const f4*)(base + i * 48 + kg * 4);
  const f4 bsz = *(const f4*)(base + i * 48 + 16 + kg * 4);
  const f4 bsn = *(const f4*)(base + i * 48 + 32 + kg * 4);
  const f4 bnv = *(const f4*)(bn_e + t * 16 + kg * 4);

  f4 acc = {0.0f, 0.0f, 0.0f, 0.0f};
  const f4 zero = {0.0f, 0.0f, 0.0f, 0.0f};

#pragma unroll
  for (int tt = 0; tt < 4; ++tt) {
    const f4 ev = evs[tt];
    const h4 yv = yvs[tt];
    const float aij = as[tt];

    h4 bf;
#pragma unroll
    for (int q = 0; q < 4; ++q) bf[q] = (_Float16)ev[q];

    f4 dr = __builtin_amdgcn_mfma_f32_16x16x16f16(ar, bf, zero, 0, 0, 0);
    f4 dz = __builtin_amdgcn_mfma_f32_16x16x16f16(az, bf, zero, 0, 0, 0);
    f4 dh = __builtin_amdgcn_mfma_f32_16x16x16f16(an, bf, zero, 0, 0, 0);
    dr = __builtin_amdgcn_mfma_f32_16x16x16f16(cr, yv, dr, 0, 0, 0);
    dz = __builtin_amdgcn_mfma_f32_16x16x16f16(cz, yv, dz, 0, 0, 0);
    const f4 di = __builtin_amdgcn_mfma_f32_16x16x16f16(cn, yv, zero, 0, 0, 0);

#pragma unroll
    for (int q = 0; q < 4; ++q) acc[q] = fmaf(ev[q], aij, acc[q]);

    float* op = e_new + (erow + jb + tt * 16) * 16 + kg * 4;
#pragma unroll
    for (int q = 0; q < 4; ++q) {
      const float rg = sig_(bsr[q] + dr[q]);
      const float zg = sig_(bsz[q] + dz[q]);
      const float ng = tanh_(bsn[q] + di[q] + rg * (dh[q] + bnv[q]));
      __builtin_nontemporal_store(ng + zg * (ev[q] - ng), op + q);  // never re-read: keep out of L2/L3
    }
  }

  // rowsum partial: reduce over the 16 lanes of each kg-group.
#pragma unroll
  for (int m = 1; m <= 8; m <<= 1) {
#pragma unroll
    for (int q = 0; q < 4; ++q) acc[q] += __shfl_xor(acc[q], m, 64);
  }
  if (lj == 0) {
#pragma unroll
    for (int q = 0; q < 4; ++q) red[wid][kg * 4 + q] = acc[q];
  }
  __syncthreads();
  if (tid < 16)
    rowsum_part[(i * NSPLIT + s) * 16 + tid] =
        red[0][tid] + red[1][tid] + red[2][tid] + red[3][tid];

  // ---- last-block-done: the 4th block for row i runs the node GRU ----
  if (tid == 0) {
    __threadfence();                      // release: parts visible before count bump
    lastflag = (atomicAdd(&cnt[i], 1) == NSPLIT - 1);
  }
  __syncthreads();
  if (lastflag) {
    __threadfence();                      // acquire: see other blocks' parts
    if (tid < 16) {
      const float* rp = rowsum_part + (i * NSPLIT) * 16 + tid;
      float rs2 = rp[0] + rp[16] + rp[32] + rp[48];
      float xv = y[i * 16 + tid] * rs2;
      if (i < NOBS_ && tid == 0) xv = obs[i];
      red[0][tid] = xv;
    }
    __syncthreads();
    if (tid < 32) {
      const int d = tid;
      const float* wi = w_ih_n + t * 96 * 16;
      const float* wh = w_hh_n + t * 96 * 32;
      const float* hp = hsrc + i * 32;
      float ir = b_n[t * 96 + d], iz = b_n[t * 96 + 32 + d], in_ = b_n[t * 96 + 64 + d];
#pragma unroll
      for (int q = 0; q < 16; ++q) {
        const float xq = red[0][q];
        ir = fmaf(wi[d * 16 + q], xq, ir);
        iz = fmaf(wi[(32 + d) * 16 + q], xq, iz);
        in_ = fmaf(wi[(64 + d) * 16 + q], xq, in_);
      }
      float hr = 0.0f, hz = 0.0f, hn = 0.0f;
#pragma unroll
      for (int q = 0; q < 32; ++q) {
        hr = fmaf(wh[d * 32 + q], hp[q], hr);
        hz = fmaf(wh[(32 + d) * 32 + q], hp[q], hz);
        hn = fmaf(wh[(64 + d) * 32 + q], hp[q], hn);
      }
      const float rg = sig_(ir + hr), zg = sig_(iz + hz);
      const float ng = tanh_(in_ + rg * (hn + bn_n[t * 32 + d]));
      out[1 + i * 32 + d] = ng + zg * (hp[d] - ng);
    }
  }
}

extern "C" void kernel_launch(void* const* d_in, const int* in_sizes, int n_in,
                              void* d_out, int out_size, void* d_ws, size_t ws_size,
                              hipStream_t stream) {
  const float* obs   = (const float*)d_in[0];
  const float* h     = (const float*)d_in[1];
  const int*   types = (const int*)d_in[2];
  const float* e     = (const float*)d_in[3];
  const int*   A     = (const int*)d_in[4];
  const float* r     = (const float*)d_in[5];
  const float* w_ih_n = (const float*)d_in[6];
  const float* w_hh_n = (const float*)d_in[7];
  const float* b_n    = (const float*)d_in[8];
  const float* bn_n   = (const float*)d_in[9];
  const float* W_out  = (const float*)d_in[10];
  const float* b_out  = (const float*)d_in[11];
  const float* w_ih_e = (const float*)d_in[12];
  const float* w_hh_e = (const float*)d_in[13];
  const float* b_e    = (const float*)d_in[14];
  const float* bn_e   = (const float*)d_in[15];

  float* ws = (float*)d_ws;
  float* y_buf       = ws;                            // 1024*16  f32
  float* base        = y_buf + 16384;                 // 1024*48  f32
  float* rowsum_part = base + 49152;                  // 1024*4*16 f32
  _Float16* y_h      = (_Float16*)(rowsum_part + 65536);  // 1024*16 f16
  _Float16* w16hh    = y_h + 16384;                   // 8*48*16 f16
  _Float16* w16ih    = w16hh + 6144;                  // 8*48*16 f16
  int* cnt           = (int*)(w16ih + 6144);          // 1024 int

  float* out   = (float*)d_out;
  float* out_e = out + 1 + NN * DHH;                  // e_new region (d_out + 32769)

  prep2_kernel<<<116, 256, 0, stream>>>(h, W_out, b_out, types, w_ih_e, w_hh_e,
                                        b_e, r, y_buf, y_h, base, w16hh, w16ih,
                                        cnt, out);
  edge_kernel<<<NN * NSPLIT, 256, 0, stream>>>(e, A, w16hh, w16ih, bn_e, types,
                                               base, y_h, out_e, rowsum_part,
                                               cnt, obs, h, w_ih_n, w_hh_n, b_n,
                                               bn_n, y_buf, out);
}

// Round 10
// 40.343 us; speedup vs baseline: 12.0874x; 12.0874x over previous
//
#include <hip/hip_runtime.h>
#include <math.h>

#define NN 1024
#define DHH 32
#define DEE 16
#define TT 8
#define NOBS_ 64
#define ADIM_ 10
#define NSPLIT 4   // blocks per row in edge kernel; 4 tiles of 16 j per block

typedef _Float16 h4 __attribute__((ext_vector_type(4)));
typedef float f4 __attribute__((ext_vector_type(4)));

// 1-ulp hardware reciprocal: avoids the ~10-instr IEEE division expansion.
__device__ __forceinline__ float rcp_(float x) { return __builtin_amdgcn_rcpf(x); }
__device__ __forceinline__ float sig_(float x) { return rcp_(1.0f + __expf(-x)); }
__device__ __forceinline__ float tanh_(float x) { return 1.0f - 2.0f * rcp_(1.0f + __expf(2.0f * x)); }

// Fused prep: blocks 0..63  -> y (+f16 copy) + base for 16 nodes each; block 63 also argmax -> out[0]
//             blocks 64..111-> f16 weight tables (hh identity layout, ih de-strided)
__global__ __launch_bounds__(256) void prep2_kernel(
    const float* __restrict__ h, const float* __restrict__ W_out,
    const float* __restrict__ b_out, const int* __restrict__ types,
    const float* __restrict__ w_ih_e, const float* __restrict__ w_hh_e,
    const float* __restrict__ b_e, const float* __restrict__ rs,
    float* __restrict__ y, _Float16* __restrict__ y_h,
    float* __restrict__ base, _Float16* __restrict__ w16hh,
    _Float16* __restrict__ w16ih, float* __restrict__ out) {
  const int blk = blockIdx.x;
  const int tid = threadIdx.x;
  if (blk < 64) {
    __shared__ float ys[256];
    const int ni = tid >> 4, d = tid & 15;
    const int node = blk * 16 + ni;
    const float* hp = h + node * DHH;
    const float* wp = W_out + d * DHH;
    float s = b_out[d];
#pragma unroll
    for (int q = 0; q < DHH; ++q) s = fmaf(hp[q], wp[q], s);
    s = fmaxf(s, 0.0f);
    y[node * 16 + d] = s;
    y_h[node * 16 + d] = (_Float16)s;
    ys[tid] = s;
    __syncthreads();
#pragma unroll
    for (int v0 = 0; v0 < 3; ++v0) {
      const int v = v0 * 256 + tid;           // 768 (node,k) pairs per block
      const int ni2 = v / 48, k = v - ni2 * 48;
      const int node2 = blk * 16 + ni2;
      const int t = types[node2];
      const float* w = w_ih_e + (t * 48 + k) * 33;
      float s2 = b_e[t * 48 + k] + rs[0] * w[32];
#pragma unroll
      for (int q = 0; q < DEE; ++q) s2 = fmaf(w[q], ys[ni2 * 16 + q], s2);
      base[node2 * 48 + k] = s2;
    }
    if (blk == 63 && tid == 0) {   // nodes 1014..1023 are ni 6..15 here
      int bi = 0;
      float best = ys[6 * 16];
      for (int l = 1; l < ADIM_; ++l) {
        float v = ys[(6 + l) * 16];
        if (v > best) { best = v; bi = l; }
      }
      out[0] = (float)bi;
    }
  } else {
    const int u = (blk - 64) * 256 + tid;     // < 12288
    if (u < TT * 48 * 16) {
      w16hh[u] = (_Float16)w_hh_e[u];
    } else {
      const int v = u - TT * 48 * 16;
      const int row = v >> 4, k = v & 15;
      w16ih[v] = (_Float16)w_ih_e[row * 33 + 16 + k];
    }
  }
}

// MFMA edge GRU (round-8 body: regular stores, no fence/atomic tail).
// Block b: row i = b>>2, quarter s = b&3; lane owns dims (lane>>4)*4.. of edge j.
__global__ __launch_bounds__(256, 4) void edge_kernel(
    const float* __restrict__ e, const int* __restrict__ A,
    const _Float16* __restrict__ w16hh, const _Float16* __restrict__ w16ih,
    const float* __restrict__ bn_e, const int* __restrict__ types,
    const float* __restrict__ base, const _Float16* __restrict__ yh,
    float* __restrict__ e_new, float* __restrict__ rowsum_part) {
  __shared__ float red[4][16];
  const int b = blockIdx.x;
  const int i = b >> 2;
  const int s = b & 3;
  const int tid = threadIdx.x;
  const int lane = tid & 63, wid = tid >> 6;
  const int lj = lane & 15;
  const int kg = lane >> 4;
  const int jb = s * 256 + wid * 64 + lj;
  const int erow = i * NN;

  // ---- data loads first (blockIdx-only addresses) ----
  f4 evs[4]; h4 yvs[4]; float as[4];
#pragma unroll
  for (int tt = 0; tt < 4; ++tt) {
    const int j = jb + tt * 16;
    evs[tt] = *(const f4*)(e + (erow + j) * 16 + kg * 4);
    yvs[tt] = *(const h4*)(yh + j * 16 + kg * 4);
    as[tt] = (float)A[erow + j];
  }

  // ---- type-dependent preamble (resolves under the load shadow) ----
  const int t = types[i];
  const h4 ar = *(const h4*)(w16hh + (t * 48 + lj) * 16 + kg * 4);
  const h4 az = *(const h4*)(w16hh + (t * 48 + 16 + lj) * 16 + kg * 4);
  const h4 an = *(const h4*)(w16hh + (t * 48 + 32 + lj) * 16 + kg * 4);
  const h4 cr = *(const h4*)(w16ih + (t * 48 + lj) * 16 + kg * 4);
  const h4 cz = *(const h4*)(w16ih + (t * 48 + 16 + lj) * 16 + kg * 4);
  const h4 cn = *(const h4*)(w16ih + (t * 48 + 32 + lj) * 16 + kg * 4);
  const f4 bsr = *(const f4*)(base + i * 48 + kg * 4);
  const f4 bsz = *(const f4*)(base + i * 48 + 16 + kg * 4);
  const f4 bsn = *(const f4*)(base + i * 48 + 32 + kg * 4);
  const f4 bnv = *(const f4*)(bn_e + t * 16 + kg * 4);

  f4 acc = {0.0f, 0.0f, 0.0f, 0.0f};
  const f4 zero = {0.0f, 0.0f, 0.0f, 0.0f};

#pragma unroll
  for (int tt = 0; tt < 4; ++tt) {
    const f4 ev = evs[tt];
    const h4 yv = yvs[tt];
    const float aij = as[tt];

    h4 bf;
#pragma unroll
    for (int q = 0; q < 4; ++q) bf[q] = (_Float16)ev[q];

    f4 dr = __builtin_amdgcn_mfma_f32_16x16x16f16(ar, bf, zero, 0, 0, 0);
    f4 dz = __builtin_amdgcn_mfma_f32_16x16x16f16(az, bf, zero, 0, 0, 0);
    f4 dh = __builtin_amdgcn_mfma_f32_16x16x16f16(an, bf, zero, 0, 0, 0);
    dr = __builtin_amdgcn_mfma_f32_16x16x16f16(cr, yv, dr, 0, 0, 0);
    dz = __builtin_amdgcn_mfma_f32_16x16x16f16(cz, yv, dz, 0, 0, 0);
    const f4 di = __builtin_amdgcn_mfma_f32_16x16x16f16(cn, yv, zero, 0, 0, 0);

#pragma unroll
    for (int q = 0; q < 4; ++q) acc[q] = fmaf(ev[q], aij, acc[q]);

    float* op = e_new + (erow + jb + tt * 16) * 16 + kg * 4;
#pragma unroll
    for (int q = 0; q < 4; ++q) {
      const float rg = sig_(bsr[q] + dr[q]);
      const float zg = sig_(bsz[q] + dz[q]);
      const float ng = tanh_(bsn[q] + di[q] + rg * (dh[q] + bnv[q]));
      op[q] = ng + zg * (ev[q] - ng);
    }
  }

  // rowsum partial: reduce over the 16 lanes of each kg-group.
#pragma unroll
  for (int m = 1; m <= 8; m <<= 1) {
#pragma unroll
    for (int q = 0; q < 4; ++q) acc[q] += __shfl_xor(acc[q], m, 64);
  }
  if (lj == 0) {
#pragma unroll
    for (int q = 0; q < 4; ++q) red[wid][kg * 4 + q] = acc[q];
  }
  __syncthreads();
  if (tid < 16)
    rowsum_part[(i * NSPLIT + s) * 16 + tid] =
        red[0][tid] + red[1][tid] + red[2][tid] + red[3][tid];
}

// Node GRU (32 threads per node, 8 nodes per block).
__global__ __launch_bounds__(256) void node_kernel(
    const float* __restrict__ obs, const float* __restrict__ h,
    const int* __restrict__ types, const float* __restrict__ w_ih_n,
    const float* __restrict__ w_hh_n, const float* __restrict__ b_n,
    const float* __restrict__ bn_n, const float* __restrict__ y,
    const float* __restrict__ rowsum_part, float* __restrict__ out) {
  const int tid = threadIdx.x;
  const int node = blockIdx.x * 8 + (tid >> 5);
  const int d = tid & 31;
  const int t = types[node];
  float x[16];
#pragma unroll
  for (int q = 0; q < 16; ++q) {
    const float* rp = rowsum_part + node * NSPLIT * 16 + q;
    float rs = rp[0] + rp[16] + rp[32] + rp[48];
    x[q] = y[node * 16 + q] * rs;
  }
  if (node < NOBS_) x[0] = obs[node];
  const float* wi = w_ih_n + t * 96 * 16;
  const float* wh = w_hh_n + t * 96 * 32;
  const float* hp = h + node * 32;
  float ir = b_n[t * 96 + d], iz = b_n[t * 96 + 32 + d], in_ = b_n[t * 96 + 64 + d];
#pragma unroll
  for (int q = 0; q < 16; ++q) {
    ir = fmaf(wi[d * 16 + q], x[q], ir);
    iz = fmaf(wi[(32 + d) * 16 + q], x[q], iz);
    in_ = fmaf(wi[(64 + d) * 16 + q], x[q], in_);
  }
  float hr = 0.0f, hz = 0.0f, hn = 0.0f;
#pragma unroll
  for (int q = 0; q < 32; ++q) {
    hr = fmaf(wh[d * 32 + q], hp[q], hr);
    hz = fmaf(wh[(32 + d) * 32 + q], hp[q], hz);
    hn = fmaf(wh[(64 + d) * 32 + q], hp[q], hn);
  }
  float rg = sig_(ir + hr), zg = sig_(iz + hz);
  float ng = tanh_(in_ + rg * (hn + bn_n[t * 32 + d]));
  out[1 + node * 32 + d] = ng + zg * (hp[d] - ng);
}

extern "C" void kernel_launch(void* const* d_in, const int* in_sizes, int n_in,
                              void* d_out, int out_size, void* d_ws, size_t ws_size,
                              hipStream_t stream) {
  const float* obs   = (const float*)d_in[0];
  const float* h     = (const float*)d_in[1];
  const int*   types = (const int*)d_in[2];
  const float* e     = (const float*)d_in[3];
  const int*   A     = (const int*)d_in[4];
  const float* r     = (const float*)d_in[5];
  const float* w_ih_n = (const float*)d_in[6];
  const float* w_hh_n = (const float*)d_in[7];
  const float* b_n    = (const float*)d_in[8];
  const float* bn_n   = (const float*)d_in[9];
  const float* W_out  = (const float*)d_in[10];
  const float* b_out  = (const float*)d_in[11];
  const float* w_ih_e = (const float*)d_in[12];
  const float* w_hh_e = (const float*)d_in[13];
  const float* b_e    = (const float*)d_in[14];
  const float* bn_e   = (const float*)d_in[15];

  float* ws = (float*)d_ws;
  float* y_buf       = ws;                            // 1024*16  f32
  float* base        = y_buf + 16384;                 // 1024*48  f32
  float* rowsum_part = base + 49152;                  // 1024*4*16 f32
  _Float16* y_h      = (_Float16*)(rowsum_part + 65536);  // 1024*16 f16
  _Float16* w16hh    = y_h + 16384;                   // 8*48*16 f16
  _Float16* w16ih    = w16hh + 6144;                  // 8*48*16 f16

  float* out   = (float*)d_out;
  float* out_e = out + 1 + NN * DHH;                  // e_new region (d_out + 32769)

  prep2_kernel<<<112, 256, 0, stream>>>(h, W_out, b_out, types, w_ih_e, w_hh_e,
                                        b_e, r, y_buf, y_h, base, w16hh, w16ih,
                                        out);
  edge_kernel<<<NN * NSPLIT, 256, 0, stream>>>(e, A, w16hh, w16ih, bn_e, types,
                                               base, y_h, out_e, rowsum_part);
  node_kernel<<<128, 256, 0, stream>>>(obs, h, types, w_ih_n, w_hh_n, b_n, bn_n,
                                       y_buf, rowsum_part, out);
}